// Round 1
// baseline (1040.853 us; speedup 1.0000x reference)
//
#include <hip/hip_runtime.h>
#include <math.h>

#define CC 128   // channels
// B=16, N=128 per graph, BN=2048 nodes, L=3 layers

__device__ __forceinline__ float fsilu(float x) { return x / (1.0f + __expf(-x)); }
__device__ __forceinline__ float fsigm(float x) { return 1.0f / (1.0f + __expf(-x)); }
__device__ __forceinline__ float ftanh_(float x) { return 1.0f - 2.0f / (__expf(2.0f * x) + 1.0f); }

// ---------------------------------------------------------------- init ------
// h0[n][c] = mask*(W[atom]+W[54+pos]+W[84+aa]+W[104+sl]) + t*mask*W[130] + b
__global__ __launch_bounds__(128) void egnn_init(
    const float* __restrict__ t, const float* __restrict__ x,
    const int* __restrict__ atomt, const int* __restrict__ aapos,
    const int* __restrict__ aatype, const int* __restrict__ slen,
    const float* __restrict__ nmask, const float* __restrict__ embW,
    const float* __restrict__ embB, float* __restrict__ h,
    float* __restrict__ xf, float* __restrict__ xA)
{
    const int n = blockIdx.x;
    const int c = threadIdx.x;
    const int b = n >> 7;
    const int i = n & 127;
    const float mi = nmask[n];
    int ia = atomt[n] - 1; if (ia < 0) ia = 0;
    int ip = aapos[n] - 1; if (ip < 0) ip = 0;
    int iq = aatype[n] - 1; if (iq < 0) iq = 0;
    int is = slen[b] - 5;  if (is < 0) is = 0;
    const float tt = t[b] * mi;
    float v = mi * (embW[ia * CC + c] + embW[(54 + ip) * CC + c] +
                    embW[(84 + iq) * CC + c] + embW[(104 + is) * CC + c]) +
              tt * embW[130 * CC + c] + embB[c];
    h[(size_t)n * CC + c] = v;
    if (c < 3) {
        float xv = x[b * 384 + i * 3 + c] * mi;
        xf[3 * n + c] = xv;
        xA[3 * n + c] = xv;
    }
}

// ---------------------------------------------------------------- P,Q -------
// P[n] = h[n] @ We1[0:128] + be1 ; Q[n] = h[n] @ We1[128:256]
__global__ __launch_bounds__(128) void egnn_pq(
    const float* __restrict__ h, const float* __restrict__ We1,
    const float* __restrict__ be1, float* __restrict__ P, float* __restrict__ Q)
{
    __shared__ float hs[8][CC];
    const int c = threadIdx.x;
    const int n0 = blockIdx.x * 8;
#pragma unroll
    for (int nn = 0; nn < 8; ++nn) hs[nn][c] = h[(size_t)(n0 + nn) * CC + c];
    __syncthreads();
    float aP[8], aQ[8];
    const float bv = be1[c];
#pragma unroll
    for (int nn = 0; nn < 8; ++nn) { aP[nn] = bv; aQ[nn] = 0.f; }
    for (int k = 0; k < CC; ++k) {
        const float wr = We1[k * CC + c];
        const float wc = We1[(CC + k) * CC + c];
#pragma unroll
        for (int nn = 0; nn < 8; ++nn) {
            aP[nn] = fmaf(hs[nn][k], wr, aP[nn]);
            aQ[nn] = fmaf(hs[nn][k], wc, aQ[nn]);
        }
    }
#pragma unroll
    for (int nn = 0; nn < 8; ++nn) {
        P[(size_t)(n0 + nn) * CC + c] = aP[nn];
        Q[(size_t)(n0 + nn) * CC + c] = aQ[nn];
    }
}

// ------------------------------------------------------------- edge GEMM ----
// out[j][c] = sum_k Ms[j][k] * W[k][c]; Ms row stride 129 (bank-conflict-free)
__device__ __forceinline__ void gemm128x128(const float* __restrict__ W,
    const float* Ms, float* WT, int j0, int c0, int tid, float acc[8][8])
{
#pragma unroll
    for (int jj = 0; jj < 8; ++jj)
#pragma unroll
        for (int cc = 0; cc < 8; ++cc) acc[jj][cc] = 0.f;
    for (int kt = 0; kt < 8; ++kt) {
        __syncthreads();
        {
            const int r = tid >> 4;
            const int cb = (tid & 15) << 3;
            const float* src = W + (kt * 16 + r) * CC + cb;
            float4 w0 = *reinterpret_cast<const float4*>(src);
            float4 w1 = *reinterpret_cast<const float4*>(src + 4);
            *reinterpret_cast<float4*>(WT + r * CC + cb) = w0;
            *reinterpret_cast<float4*>(WT + r * CC + cb + 4) = w1;
        }
        __syncthreads();
#pragma unroll
        for (int kk = 0; kk < 16; ++kk) {
            const int k = kt * 16 + kk;
            float a[8];
#pragma unroll
            for (int jj = 0; jj < 8; ++jj) a[jj] = Ms[(j0 + jj) * 129 + k];
            float4 b0 = *reinterpret_cast<const float4*>(WT + kk * CC + c0);
            float4 b1 = *reinterpret_cast<const float4*>(WT + kk * CC + c0 + 4);
            float bb[8] = {b0.x, b0.y, b0.z, b0.w, b1.x, b1.y, b1.z, b1.w};
#pragma unroll
            for (int jj = 0; jj < 8; ++jj)
#pragma unroll
                for (int cc = 0; cc < 8; ++cc)
                    acc[jj][cc] = fmaf(a[jj], bb[cc], acc[jj][cc]);
        }
    }
    __syncthreads();
}

// ---------------------------------------------------------------- edge ------
// One block per (graph b, row i): all 128 edges (i,j).
__global__ __launch_bounds__(256) void egnn_edge(
    const float* __restrict__ P, const float* __restrict__ Q,
    const float* __restrict__ xcur, const float* __restrict__ xf,
    const float* __restrict__ nmask, const float* __restrict__ We1t,
    const float* __restrict__ We2, const float* __restrict__ be2,
    const float* __restrict__ Wa, const float* __restrict__ ba,
    const float* __restrict__ Wc1, const float* __restrict__ bc1,
    const float* __restrict__ Wc2,
    float* __restrict__ xnext, float* __restrict__ agg)
{
    extern __shared__ float sm[];
    float* Ms    = sm;                  // 128*129
    float* WT    = Ms + 128 * 129;      // 16*128
    float* diffs = WT + 16 * 128;       // 128*3
    float* rj    = diffs + 384;         // 128
    float* eaj   = rj + 128;            // 128
    float* emk   = eaj + 128;           // 128
    float* pi    = emk + 128;           // 128
    float* wrad  = pi + 128;            // 128
    float* wea   = wrad + 128;          // 128
    float* was   = wea + 128;           // 128
    float* wc2s  = was + 128;           // 128
    float* be2s  = wc2s + 128;          // 128
    float* bc1s  = be2s + 128;          // 128
    float* trp   = bc1s + 128;          // 16*4

    const int tid = threadIdx.x;
    const int n = blockIdx.x;
    const int b = n >> 7;
    const int i = n & 127;
    const int nb = b << 7;
    const float mi = nmask[n];

    if (tid < 128) {
        const int j = tid;
        const float xi0 = xcur[3 * n], xi1 = xcur[3 * n + 1], xi2 = xcur[3 * n + 2];
        const float xj0 = xcur[3 * (nb + j)], xj1 = xcur[3 * (nb + j) + 1], xj2 = xcur[3 * (nb + j) + 2];
        const float d0 = xi0 - xj0, d1 = xi1 - xj1, d2 = xi2 - xj2;
        diffs[3 * j] = d0; diffs[3 * j + 1] = d1; diffs[3 * j + 2] = d2;
        rj[j] = d0 * d0 + d1 * d1 + d2 * d2;
        const float f0 = xf[3 * n] - xf[3 * (nb + j)];
        const float f1 = xf[3 * n + 1] - xf[3 * (nb + j) + 1];
        const float f2 = xf[3 * n + 2] - xf[3 * (nb + j) + 2];
        eaj[j] = f0 * f0 + f1 * f1 + f2 * f2;
        emk[j] = mi * nmask[nb + j] * ((j == i) ? 0.0f : 1.0f);
    } else {
        const int c = tid - 128;
        pi[c]   = P[(size_t)n * CC + c];
        wrad[c] = We1t[c];
        wea[c]  = We1t[CC + c];
        was[c]  = Wa[c];
        wc2s[c] = Wc2[c];
        be2s[c] = be2[c];
        bc1s[c] = bc1[c];
    }
    __syncthreads();

    // Phase A: M1[j][c] = silu(p_i[c] + q_j[c] + r_j*wrad[c] + ea_j*wea[c])
    {
        const float4* Qr = reinterpret_cast<const float4*>(Q + (size_t)nb * CC);
#pragma unroll
        for (int it = 0; it < 16; ++it) {
            const int f4 = it * 256 + tid;
            const int j = f4 >> 5;
            const int c = (f4 & 31) << 2;
            float4 qv = Qr[f4];
            const float r = rj[j], ea = eaj[j];
            Ms[j * 129 + c    ] = fsilu(pi[c    ] + qv.x + r * wrad[c    ] + ea * wea[c    ]);
            Ms[j * 129 + c + 1] = fsilu(pi[c + 1] + qv.y + r * wrad[c + 1] + ea * wea[c + 1]);
            Ms[j * 129 + c + 2] = fsilu(pi[c + 2] + qv.z + r * wrad[c + 2] + ea * wea[c + 2]);
            Ms[j * 129 + c + 3] = fsilu(pi[c + 3] + qv.w + r * wrad[c + 3] + ea * wea[c + 3]);
        }
    }
    // (gemm starts with __syncthreads -> M1 writes visible before reads)

    const int ty = tid >> 4, tx = tid & 15;
    const int j0 = ty << 3, c0 = tx << 3;
    float acc[8][8];

    // Phase B: M2 = silu(M1 @ We2 + be2); gate; write m back to Ms
    gemm128x128(We2, Ms, WT, j0, c0, tid, acc);
    float pa[8];
#pragma unroll
    for (int jj = 0; jj < 8; ++jj) {
        float s = 0.f;
#pragma unroll
        for (int cc = 0; cc < 8; ++cc) {
            float v = fsilu(acc[jj][cc] + be2s[c0 + cc]);
            acc[jj][cc] = v;
            s = fmaf(v, was[c0 + cc], s);
        }
        pa[jj] = s;
    }
#pragma unroll
    for (int o = 1; o < 16; o <<= 1)
#pragma unroll
        for (int jj = 0; jj < 8; ++jj) pa[jj] += __shfl_xor(pa[jj], o, 64);
    const float bav = ba[0];
#pragma unroll
    for (int jj = 0; jj < 8; ++jj) {
        const float g = fsigm(pa[jj] + bav) * emk[j0 + jj];
#pragma unroll
        for (int cc = 0; cc < 8; ++cc) {
            const float v = acc[jj][cc] * g;
            acc[jj][cc] = v;
            Ms[(j0 + jj) * 129 + c0 + cc] = v;
        }
    }
    __syncthreads();

    // agg_i[c] = sum_j m[j][c]
    if (tid < 128) {
        float s = 0.f;
#pragma unroll 8
        for (int j = 0; j < 128; ++j) s += Ms[j * 129 + tid];
        agg[(size_t)n * CC + tid] = s;
    }

    // Phase C: Cmat = silu(m @ Wc1 + bc1); tsc_j = tanh(Cmat[j].Wc2); trans
    gemm128x128(Wc1, Ms, WT, j0, c0, tid, acc);
    float dt[8];
#pragma unroll
    for (int jj = 0; jj < 8; ++jj) {
        float s = 0.f;
#pragma unroll
        for (int cc = 0; cc < 8; ++cc)
            s = fmaf(fsilu(acc[jj][cc] + bc1s[c0 + cc]), wc2s[c0 + cc], s);
        dt[jj] = s;
    }
#pragma unroll
    for (int o = 1; o < 16; o <<= 1)
#pragma unroll
        for (int jj = 0; jj < 8; ++jj) dt[jj] += __shfl_xor(dt[jj], o, 64);
    if (tx == 0) {
        float t0 = 0.f, t1 = 0.f, t2 = 0.f;
#pragma unroll
        for (int jj = 0; jj < 8; ++jj) {
            const float ts = ftanh_(dt[jj]);
            const int j = j0 + jj;
            t0 = fmaf(diffs[3 * j    ], ts, t0);
            t1 = fmaf(diffs[3 * j + 1], ts, t1);
            t2 = fmaf(diffs[3 * j + 2], ts, t2);
        }
        trp[ty * 4 + 0] = t0; trp[ty * 4 + 1] = t1; trp[ty * 4 + 2] = t2;
    }
    __syncthreads();
    if (tid < 3) {
        float s = 0.f;
#pragma unroll
        for (int w = 0; w < 16; ++w) s += trp[w * 4 + tid];
        xnext[3 * n + tid] = (xcur[3 * n + tid] + s) * mi;
    }
}

// ---------------------------------------------------------------- node ------
// hn = silu([h|agg] @ Wn1 + bn1) @ Wn2 + bn2; h = (h + hn) * mask
__global__ __launch_bounds__(128) void egnn_node(
    float* __restrict__ h, const float* __restrict__ agg,
    const float* __restrict__ nmask,
    const float* __restrict__ Wn1, const float* __restrict__ bn1,
    const float* __restrict__ Wn2, const float* __restrict__ bn2)
{
    __shared__ float hs[8][CC], as_[8][CC], hn[8][CC];
    const int c = threadIdx.x;
    const int n0 = blockIdx.x * 8;
#pragma unroll
    for (int nn = 0; nn < 8; ++nn) {
        hs[nn][c]  = h[(size_t)(n0 + nn) * CC + c];
        as_[nn][c] = agg[(size_t)(n0 + nn) * CC + c];
    }
    __syncthreads();
    float acc[8];
#pragma unroll
    for (int nn = 0; nn < 8; ++nn) acc[nn] = bn1[c];
    for (int k = 0; k < CC; ++k) {
        const float w = Wn1[k * CC + c];
#pragma unroll
        for (int nn = 0; nn < 8; ++nn) acc[nn] = fmaf(hs[nn][k], w, acc[nn]);
    }
    for (int k = 0; k < CC; ++k) {
        const float w = Wn1[(CC + k) * CC + c];
#pragma unroll
        for (int nn = 0; nn < 8; ++nn) acc[nn] = fmaf(as_[nn][k], w, acc[nn]);
    }
#pragma unroll
    for (int nn = 0; nn < 8; ++nn) hn[nn][c] = fsilu(acc[nn]);
    __syncthreads();
#pragma unroll
    for (int nn = 0; nn < 8; ++nn) acc[nn] = bn2[c];
    for (int k = 0; k < CC; ++k) {
        const float w = Wn2[k * CC + c];
#pragma unroll
        for (int nn = 0; nn < 8; ++nn) acc[nn] = fmaf(hn[nn][k], w, acc[nn]);
    }
#pragma unroll
    for (int nn = 0; nn < 8; ++nn)
        h[(size_t)(n0 + nn) * CC + c] = (hs[nn][c] + acc[nn]) * nmask[n0 + nn];
}

// ---------------------------------------------------------------- final -----
__global__ __launch_bounds__(128) void egnn_final(
    const float* __restrict__ xcur, const float* __restrict__ xf,
    const float* __restrict__ nmask, float* __restrict__ out)
{
    __shared__ float red[128][4];
    const int i = threadIdx.x, b = blockIdx.x;
    const int n = b * 128 + i;
    const float mi = nmask[n];
    const float v0 = (xcur[3 * n    ] - xf[3 * n    ]) * mi;
    const float v1 = (xcur[3 * n + 1] - xf[3 * n + 1]) * mi;
    const float v2 = (xcur[3 * n + 2] - xf[3 * n + 2]) * mi;
    red[i][0] = v0; red[i][1] = v1; red[i][2] = v2; red[i][3] = mi;
    __syncthreads();
    for (int s = 64; s > 0; s >>= 1) {
        if (i < s) {
            red[i][0] += red[i + s][0]; red[i][1] += red[i + s][1];
            red[i][2] += red[i + s][2]; red[i][3] += red[i + s][3];
        }
        __syncthreads();
    }
    const float inv = 1.0f / red[0][3];
    out[b * 384 + i * 3 + 0] = v0 - red[0][0] * inv * mi;
    out[b * 384 + i * 3 + 1] = v1 - red[0][1] * inv * mi;
    out[b * 384 + i * 3 + 2] = v2 - red[0][2] * inv * mi;
}

// ---------------------------------------------------------------- host ------
extern "C" void kernel_launch(void* const* d_in, const int* in_sizes, int n_in,
                              void* d_out, int out_size, void* d_ws, size_t ws_size,
                              hipStream_t stream) {
    const float* t     = (const float*)d_in[0];
    const float* x     = (const float*)d_in[1];
    const int*   atomt = (const int*)d_in[2];
    const int*   aapos = (const int*)d_in[3];
    const int*   aatyp = (const int*)d_in[4];
    const int*   slen  = (const int*)d_in[5];
    const float* nmask = (const float*)d_in[6];
    const float* embW  = (const float*)d_in[7];
    const float* embB  = (const float*)d_in[8];
    const float* We1   = (const float*)d_in[9];
    const float* be1   = (const float*)d_in[10];
    const float* We2   = (const float*)d_in[11];
    const float* be2   = (const float*)d_in[12];
    const float* Wa    = (const float*)d_in[13];
    const float* ba    = (const float*)d_in[14];
    const float* Wn1   = (const float*)d_in[15];
    const float* bn1   = (const float*)d_in[16];
    const float* Wn2   = (const float*)d_in[17];
    const float* bn2   = (const float*)d_in[18];
    const float* Wc1   = (const float*)d_in[19];
    const float* bc1   = (const float*)d_in[20];
    const float* Wc2   = (const float*)d_in[21];

    float* ws  = (float*)d_ws;
    float* h   = ws;                 // 2048*128
    float* P   = ws + 262144;        // 2048*128
    float* Q   = ws + 524288;        // 2048*128
    float* agg = ws + 786432;        // 2048*128
    float* xA  = ws + 1048576;       // 2048*3
    float* xB  = ws + 1054720;       // 2048*3
    float* xf  = ws + 1060864;       // 2048*3
    float* out = (float*)d_out;

    egnn_init<<<2048, 128, 0, stream>>>(t, x, atomt, aapos, aatyp, slen, nmask,
                                        embW, embB, h, xf, xA);

    const size_t edge_lds = 20288 * sizeof(float);  // 81,152 B -> 2 blocks/CU
    float* xc = xA;
    float* xn = xB;
    for (int l = 0; l < 3; ++l) {
        egnn_pq<<<256, 128, 0, stream>>>(h, We1 + (size_t)l * 258 * CC,
                                         be1 + l * CC, P, Q);
        egnn_edge<<<2048, 256, edge_lds, stream>>>(
            P, Q, xc, xf, nmask,
            We1 + (size_t)l * 258 * CC + 256 * CC,   // rows 256,257: w_rad, w_ea
            We2 + (size_t)l * CC * CC, be2 + l * CC,
            Wa + l * CC, ba + l,
            Wc1 + (size_t)l * CC * CC, bc1 + l * CC,
            Wc2 + l * CC,
            xn, agg);
        egnn_node<<<256, 128, 0, stream>>>(h, agg, nmask,
                                           Wn1 + (size_t)l * 2 * CC * CC, bn1 + l * CC,
                                           Wn2 + (size_t)l * CC * CC, bn2 + l * CC);
        float* tmp = xc; xc = xn; xn = tmp;
    }
    egnn_final<<<16, 128, 0, stream>>>(xc, xf, nmask, out);
}

// Round 3
// 940.972 us; speedup vs baseline: 1.1061x; 1.1061x over previous
//
#include <hip/hip_runtime.h>
#include <math.h>

#define CC 128   // channels
#define SMS 132  // Ms row stride in floats (16B-aligned rows + 4-float pad)
// B=16, N=128 per graph, BN=2048 nodes, L=3 layers

__device__ __forceinline__ float fsilu(float x) { return x / (1.0f + __expf(-x)); }
__device__ __forceinline__ float fsigm(float x) { return 1.0f / (1.0f + __expf(-x)); }
__device__ __forceinline__ float ftanh_(float x) { return 1.0f - 2.0f / (__expf(2.0f * x) + 1.0f); }

// Swizzled Ms index: XOR float-col bits 2-3 with row-group -> conflict-free
// b128 A-reads (4 ty-groups land on 4 distinct bank-quads).
__device__ __forceinline__ int msx(int j, int c) {
    return j * SMS + (c ^ (((j >> 3) & 3) << 2));
}

// ---------------------------------------------------------------- init ------
__global__ __launch_bounds__(128) void egnn_init(
    const float* __restrict__ t, const float* __restrict__ x,
    const int* __restrict__ atomt, const int* __restrict__ aapos,
    const int* __restrict__ aatype, const int* __restrict__ slen,
    const float* __restrict__ nmask, const float* __restrict__ embW,
    const float* __restrict__ embB, float* __restrict__ h,
    float* __restrict__ xf, float* __restrict__ xA)
{
    const int n = blockIdx.x;
    const int c = threadIdx.x;
    const int b = n >> 7;
    const int i = n & 127;
    const float mi = nmask[n];
    int ia = atomt[n] - 1; if (ia < 0) ia = 0;
    int ip = aapos[n] - 1; if (ip < 0) ip = 0;
    int iq = aatype[n] - 1; if (iq < 0) iq = 0;
    int is = slen[b] - 5;  if (is < 0) is = 0;
    const float tt = t[b] * mi;
    float v = mi * (embW[ia * CC + c] + embW[(54 + ip) * CC + c] +
                    embW[(84 + iq) * CC + c] + embW[(104 + is) * CC + c]) +
              tt * embW[130 * CC + c] + embB[c];
    h[(size_t)n * CC + c] = v;
    if (c < 3) {
        float xv = x[b * 384 + i * 3 + c] * mi;
        xf[3 * n + c] = xv;
        xA[3 * n + c] = xv;
    }
}

// ---------------------------------------------------------------- P,Q -------
__global__ __launch_bounds__(128) void egnn_pq(
    const float* __restrict__ h, const float* __restrict__ We1,
    const float* __restrict__ be1, float* __restrict__ P, float* __restrict__ Q)
{
    __shared__ float hs[8][CC];
    const int c = threadIdx.x;
    const int n0 = blockIdx.x * 8;
#pragma unroll
    for (int nn = 0; nn < 8; ++nn) hs[nn][c] = h[(size_t)(n0 + nn) * CC + c];
    __syncthreads();
    float aP[8], aQ[8];
    const float bv = be1[c];
#pragma unroll
    for (int nn = 0; nn < 8; ++nn) { aP[nn] = bv; aQ[nn] = 0.f; }
    for (int k = 0; k < CC; ++k) {
        const float wr = We1[k * CC + c];
        const float wc = We1[(CC + k) * CC + c];
#pragma unroll
        for (int nn = 0; nn < 8; ++nn) {
            aP[nn] = fmaf(hs[nn][k], wr, aP[nn]);
            aQ[nn] = fmaf(hs[nn][k], wc, aQ[nn]);
        }
    }
#pragma unroll
    for (int nn = 0; nn < 8; ++nn) {
        P[(size_t)(n0 + nn) * CC + c] = aP[nn];
        Q[(size_t)(n0 + nn) * CC + c] = aQ[nn];
    }
}

// ------------------------------------------------------------- edge GEMM ----
// acc[jj][0..3] -> cols 4tx..4tx+3 ; acc[jj][4..7] -> cols 64+4tx..64+4tx+3
__device__ __forceinline__ void gemm128(const float* __restrict__ W,
    const float* Ms, float* WT, int j0, int tx, int tid, float acc[8][8])
{
#pragma unroll
    for (int jj = 0; jj < 8; ++jj)
#pragma unroll
        for (int cc = 0; cc < 8; ++cc) acc[jj][cc] = 0.f;
    const int cb = (tid & 15) << 2;
    const int r  = tid >> 4;
    for (int kt = 0; kt < 8; ++kt) {
        __syncthreads();
        {
            const float* src = W + (kt * 16 + r) * CC + cb;
            *reinterpret_cast<float4*>(WT + r * CC + cb) =
                *reinterpret_cast<const float4*>(src);
            *reinterpret_cast<float4*>(WT + r * CC + 64 + cb) =
                *reinterpret_cast<const float4*>(src + 64);
        }
        __syncthreads();
#pragma unroll
        for (int kq = 0; kq < 4; ++kq) {
            float4 a[8];
#pragma unroll
            for (int jj = 0; jj < 8; ++jj)
                a[jj] = *reinterpret_cast<const float4*>(
                            &Ms[msx(j0 + jj, kt * 16 + kq * 4)]);
#pragma unroll
            for (int kk = 0; kk < 4; ++kk) {
                const float4 b0 = *reinterpret_cast<const float4*>(
                                      WT + (kq * 4 + kk) * CC + (tx << 2));
                const float4 b1 = *reinterpret_cast<const float4*>(
                                      WT + (kq * 4 + kk) * CC + 64 + (tx << 2));
                const float bb[8] = {b0.x, b0.y, b0.z, b0.w, b1.x, b1.y, b1.z, b1.w};
#pragma unroll
                for (int jj = 0; jj < 8; ++jj) {
                    const float av = (kk == 0) ? a[jj].x : (kk == 1) ? a[jj].y
                                   : (kk == 2) ? a[jj].z : a[jj].w;
#pragma unroll
                    for (int cc = 0; cc < 8; ++cc)
                        acc[jj][cc] = fmaf(av, bb[cc], acc[jj][cc]);
                }
            }
        }
    }
    __syncthreads();
}

// ---------------------------------------------------------------- edge ------
// One block per (graph b, row i): all 128 edges (i,j).
// Ms pad cols per row j: +128 = rj, +129 = eaj, +130 = emk.
__global__ __launch_bounds__(256, 2) void egnn_edge(
    const float* __restrict__ P, const float* __restrict__ Q,
    const float* __restrict__ xcur, const float* __restrict__ xf,
    const float* __restrict__ nmask, const float* __restrict__ We1t,
    const float* __restrict__ We2, const float* __restrict__ be2,
    const float* __restrict__ Wa, const float* __restrict__ ba,
    const float* __restrict__ Wc1, const float* __restrict__ bc1,
    const float* __restrict__ Wc2,
    float* __restrict__ xnext, float* __restrict__ agg)
{
    extern __shared__ float sm[];
    float* Ms    = sm;                  // 128*132 = 16896
    float* WT    = Ms + 128 * SMS;      // 16*128  = 2048
    float* diffs = WT + 16 * CC;        // 384
    float* pi    = diffs + 384;         // 128
    float* wrad  = pi + 128;            // 128
    float* wea   = wrad + 128;          // 128
    float* was   = wea + 128;           // 128
    float* wc2s  = was + 128;           // 128
    float* be2s  = wc2s + 128;          // 128
    float* bc1s  = be2s + 128;          // 128
    float* trp   = bc1s + 128;          // 64
    // total 20288 floats = 81,152 B

    const int tid = threadIdx.x;
    const int n = blockIdx.x;
    const int b = n >> 7;
    const int i = n & 127;
    const int nb = b << 7;
    const float mi = nmask[n];

    if (tid < 128) {
        const int j = tid;
        const float xi0 = xcur[3 * n], xi1 = xcur[3 * n + 1], xi2 = xcur[3 * n + 2];
        const float xj0 = xcur[3 * (nb + j)], xj1 = xcur[3 * (nb + j) + 1], xj2 = xcur[3 * (nb + j) + 2];
        const float d0 = xi0 - xj0, d1 = xi1 - xj1, d2 = xi2 - xj2;
        diffs[3 * j] = d0; diffs[3 * j + 1] = d1; diffs[3 * j + 2] = d2;
        Ms[j * SMS + 128] = d0 * d0 + d1 * d1 + d2 * d2;          // rj
        const float f0 = xf[3 * n] - xf[3 * (nb + j)];
        const float f1 = xf[3 * n + 1] - xf[3 * (nb + j) + 1];
        const float f2 = xf[3 * n + 2] - xf[3 * (nb + j) + 2];
        Ms[j * SMS + 129] = f0 * f0 + f1 * f1 + f2 * f2;          // eaj
        Ms[j * SMS + 130] = mi * nmask[nb + j] * ((j == i) ? 0.0f : 1.0f); // emk
    } else {
        const int c = tid - 128;
        pi[c]   = P[(size_t)n * CC + c];
        wrad[c] = We1t[c];
        wea[c]  = We1t[CC + c];
        was[c]  = Wa[c];
        wc2s[c] = Wc2[c];
        be2s[c] = be2[c];
        bc1s[c] = bc1[c];
    }
    __syncthreads();

    // Phase A: M1[j][c] = silu(p_i[c] + q_j[c] + r_j*wrad[c] + ea_j*wea[c])
    {
        const float4* Qr = reinterpret_cast<const float4*>(Q + (size_t)nb * CC);
#pragma unroll
        for (int it = 0; it < 16; ++it) {
            const int f4 = it * 256 + tid;
            const int j = f4 >> 5;
            const int c4 = (f4 & 31) << 2;
            const float4 qv = Qr[f4];
            const float r  = Ms[j * SMS + 128];
            const float ea = Ms[j * SMS + 129];
            const float4 pv = *reinterpret_cast<const float4*>(&pi[c4]);
            const float4 wr = *reinterpret_cast<const float4*>(&wrad[c4]);
            const float4 we = *reinterpret_cast<const float4*>(&wea[c4]);
            float4 o;
            o.x = fsilu(pv.x + qv.x + r * wr.x + ea * we.x);
            o.y = fsilu(pv.y + qv.y + r * wr.y + ea * we.y);
            o.z = fsilu(pv.z + qv.z + r * wr.z + ea * we.z);
            o.w = fsilu(pv.w + qv.w + r * wr.w + ea * we.w);
            *reinterpret_cast<float4*>(&Ms[msx(j, c4)]) = o;
        }
    }
    // (gemm starts with __syncthreads -> M1 writes visible before reads)

    const int ty = tid >> 4, tx = tid & 15;
    const int j0 = ty << 3;
    const int colA = tx << 2, colB = 64 + (tx << 2);
    float acc[8][8];

    // Phase B: M2 = silu(M1 @ We2 + be2); gate; write m back to Ms
    gemm128(We2, Ms, WT, j0, tx, tid, acc);
    {
        const float4 beA = *reinterpret_cast<const float4*>(&be2s[colA]);
        const float4 beB = *reinterpret_cast<const float4*>(&be2s[colB]);
        const float4 waA = *reinterpret_cast<const float4*>(&was[colA]);
        const float4 waB = *reinterpret_cast<const float4*>(&was[colB]);
        float pa[8];
#pragma unroll
        for (int jj = 0; jj < 8; ++jj) {
            float v0 = fsilu(acc[jj][0] + beA.x); float v1 = fsilu(acc[jj][1] + beA.y);
            float v2 = fsilu(acc[jj][2] + beA.z); float v3 = fsilu(acc[jj][3] + beA.w);
            float v4 = fsilu(acc[jj][4] + beB.x); float v5 = fsilu(acc[jj][5] + beB.y);
            float v6 = fsilu(acc[jj][6] + beB.z); float v7 = fsilu(acc[jj][7] + beB.w);
            acc[jj][0] = v0; acc[jj][1] = v1; acc[jj][2] = v2; acc[jj][3] = v3;
            acc[jj][4] = v4; acc[jj][5] = v5; acc[jj][6] = v6; acc[jj][7] = v7;
            pa[jj] = v0 * waA.x + v1 * waA.y + v2 * waA.z + v3 * waA.w
                   + v4 * waB.x + v5 * waB.y + v6 * waB.z + v7 * waB.w;
        }
#pragma unroll
        for (int o = 1; o < 16; o <<= 1)
#pragma unroll
            for (int jj = 0; jj < 8; ++jj) pa[jj] += __shfl_xor(pa[jj], o, 64);
        const float bav = ba[0];
#pragma unroll
        for (int jj = 0; jj < 8; ++jj) {
            const float g = fsigm(pa[jj] + bav) * Ms[(j0 + jj) * SMS + 130];
            float4 w0, w1;
            w0.x = acc[jj][0] * g; w0.y = acc[jj][1] * g;
            w0.z = acc[jj][2] * g; w0.w = acc[jj][3] * g;
            w1.x = acc[jj][4] * g; w1.y = acc[jj][5] * g;
            w1.z = acc[jj][6] * g; w1.w = acc[jj][7] * g;
            *reinterpret_cast<float4*>(&Ms[msx(j0 + jj, colA)]) = w0;
            *reinterpret_cast<float4*>(&Ms[msx(j0 + jj, colB)]) = w1;
        }
    }
    __syncthreads();

    // agg_i[c] = sum_j m[j][c]
    if (tid < 128) {
        float s = 0.f;
#pragma unroll 16
        for (int j = 0; j < 128; ++j) s += Ms[msx(j, tid)];
        agg[(size_t)n * CC + tid] = s;
    }

    // Phase C: Cmat = silu(m @ Wc1 + bc1); tsc_j = tanh(Cmat[j].Wc2); trans
    gemm128(Wc1, Ms, WT, j0, tx, tid, acc);
    {
        const float4 bcA = *reinterpret_cast<const float4*>(&bc1s[colA]);
        const float4 bcB = *reinterpret_cast<const float4*>(&bc1s[colB]);
        const float4 wcA = *reinterpret_cast<const float4*>(&wc2s[colA]);
        const float4 wcB = *reinterpret_cast<const float4*>(&wc2s[colB]);
        float dt[8];
#pragma unroll
        for (int jj = 0; jj < 8; ++jj) {
            dt[jj] = fsilu(acc[jj][0] + bcA.x) * wcA.x
                   + fsilu(acc[jj][1] + bcA.y) * wcA.y
                   + fsilu(acc[jj][2] + bcA.z) * wcA.z
                   + fsilu(acc[jj][3] + bcA.w) * wcA.w
                   + fsilu(acc[jj][4] + bcB.x) * wcB.x
                   + fsilu(acc[jj][5] + bcB.y) * wcB.y
                   + fsilu(acc[jj][6] + bcB.z) * wcB.z
                   + fsilu(acc[jj][7] + bcB.w) * wcB.w;
        }
#pragma unroll
        for (int o = 1; o < 16; o <<= 1)
#pragma unroll
            for (int jj = 0; jj < 8; ++jj) dt[jj] += __shfl_xor(dt[jj], o, 64);
        if (tx == 0) {
            float t0 = 0.f, t1 = 0.f, t2 = 0.f;
#pragma unroll
            for (int jj = 0; jj < 8; ++jj) {
                const float ts = ftanh_(dt[jj]);
                const int j = j0 + jj;
                t0 = fmaf(diffs[3 * j    ], ts, t0);
                t1 = fmaf(diffs[3 * j + 1], ts, t1);
                t2 = fmaf(diffs[3 * j + 2], ts, t2);
            }
            trp[ty * 4 + 0] = t0; trp[ty * 4 + 1] = t1; trp[ty * 4 + 2] = t2;
        }
    }
    __syncthreads();
    if (tid < 3) {
        float s = 0.f;
#pragma unroll
        for (int w = 0; w < 16; ++w) s += trp[w * 4 + tid];
        xnext[3 * n + tid] = (xcur[3 * n + tid] + s) * mi;
    }
}

// ---------------------------------------------------------------- node ------
__global__ __launch_bounds__(128) void egnn_node(
    float* __restrict__ h, const float* __restrict__ agg,
    const float* __restrict__ nmask,
    const float* __restrict__ Wn1, const float* __restrict__ bn1,
    const float* __restrict__ Wn2, const float* __restrict__ bn2)
{
    __shared__ float hs[8][CC], as_[8][CC], hn[8][CC];
    const int c = threadIdx.x;
    const int n0 = blockIdx.x * 8;
#pragma unroll
    for (int nn = 0; nn < 8; ++nn) {
        hs[nn][c]  = h[(size_t)(n0 + nn) * CC + c];
        as_[nn][c] = agg[(size_t)(n0 + nn) * CC + c];
    }
    __syncthreads();
    float acc[8];
#pragma unroll
    for (int nn = 0; nn < 8; ++nn) acc[nn] = bn1[c];
    for (int k = 0; k < CC; ++k) {
        const float w = Wn1[k * CC + c];
#pragma unroll
        for (int nn = 0; nn < 8; ++nn) acc[nn] = fmaf(hs[nn][k], w, acc[nn]);
    }
    for (int k = 0; k < CC; ++k) {
        const float w = Wn1[(CC + k) * CC + c];
#pragma unroll
        for (int nn = 0; nn < 8; ++nn) acc[nn] = fmaf(as_[nn][k], w, acc[nn]);
    }
#pragma unroll
    for (int nn = 0; nn < 8; ++nn) hn[nn][c] = fsilu(acc[nn]);
    __syncthreads();
#pragma unroll
    for (int nn = 0; nn < 8; ++nn) acc[nn] = bn2[c];
    for (int k = 0; k < CC; ++k) {
        const float w = Wn2[k * CC + c];
#pragma unroll
        for (int nn = 0; nn < 8; ++nn) acc[nn] = fmaf(hn[nn][k], w, acc[nn]);
    }
#pragma unroll
    for (int nn = 0; nn < 8; ++nn)
        h[(size_t)(n0 + nn) * CC + c] = (hs[nn][c] + acc[nn]) * nmask[n0 + nn];
}

// ---------------------------------------------------------------- final -----
__global__ __launch_bounds__(128) void egnn_final(
    const float* __restrict__ xcur, const float* __restrict__ xf,
    const float* __restrict__ nmask, float* __restrict__ out)
{
    __shared__ float red[128][4];
    const int i = threadIdx.x, b = blockIdx.x;
    const int n = b * 128 + i;
    const float mi = nmask[n];
    const float v0 = (xcur[3 * n    ] - xf[3 * n    ]) * mi;
    const float v1 = (xcur[3 * n + 1] - xf[3 * n + 1]) * mi;
    const float v2 = (xcur[3 * n + 2] - xf[3 * n + 2]) * mi;
    red[i][0] = v0; red[i][1] = v1; red[i][2] = v2; red[i][3] = mi;
    __syncthreads();
    for (int s = 64; s > 0; s >>= 1) {
        if (i < s) {
            red[i][0] += red[i + s][0]; red[i][1] += red[i + s][1];
            red[i][2] += red[i + s][2]; red[i][3] += red[i + s][3];
        }
        __syncthreads();
    }
    const float inv = 1.0f / red[0][3];
    out[b * 384 + i * 3 + 0] = v0 - red[0][0] * inv * mi;
    out[b * 384 + i * 3 + 1] = v1 - red[0][1] * inv * mi;
    out[b * 384 + i * 3 + 2] = v2 - red[0][2] * inv * mi;
}

// ---------------------------------------------------------------- host ------
extern "C" void kernel_launch(void* const* d_in, const int* in_sizes, int n_in,
                              void* d_out, int out_size, void* d_ws, size_t ws_size,
                              hipStream_t stream) {
    const float* t     = (const float*)d_in[0];
    const float* x     = (const float*)d_in[1];
    const int*   atomt = (const int*)d_in[2];
    const int*   aapos = (const int*)d_in[3];
    const int*   aatyp = (const int*)d_in[4];
    const int*   slen  = (const int*)d_in[5];
    const float* nmask = (const float*)d_in[6];
    const float* embW  = (const float*)d_in[7];
    const float* embB  = (const float*)d_in[8];
    const float* We1   = (const float*)d_in[9];
    const float* be1   = (const float*)d_in[10];
    const float* We2   = (const float*)d_in[11];
    const float* be2   = (const float*)d_in[12];
    const float* Wa    = (const float*)d_in[13];
    const float* ba    = (const float*)d_in[14];
    const float* Wn1   = (const float*)d_in[15];
    const float* bn1   = (const float*)d_in[16];
    const float* Wn2   = (const float*)d_in[17];
    const float* bn2   = (const float*)d_in[18];
    const float* Wc1   = (const float*)d_in[19];
    const float* bc1   = (const float*)d_in[20];
    const float* Wc2   = (const float*)d_in[21];

    float* ws  = (float*)d_ws;
    float* h   = ws;                 // 2048*128
    float* P   = ws + 262144;        // 2048*128
    float* Q   = ws + 524288;        // 2048*128
    float* agg = ws + 786432;        // 2048*128
    float* xA  = ws + 1048576;       // 2048*3
    float* xB  = ws + 1054720;       // 2048*3
    float* xf  = ws + 1060864;       // 2048*3
    float* out = (float*)d_out;

    egnn_init<<<2048, 128, 0, stream>>>(t, x, atomt, aapos, aatyp, slen, nmask,
                                        embW, embB, h, xf, xA);

    const size_t edge_lds = 20288 * sizeof(float);  // 81,152 B
    float* xc = xA;
    float* xn = xB;
    for (int l = 0; l < 3; ++l) {
        egnn_pq<<<256, 128, 0, stream>>>(h, We1 + (size_t)l * 258 * CC,
                                         be1 + l * CC, P, Q);
        egnn_edge<<<2048, 256, edge_lds, stream>>>(
            P, Q, xc, xf, nmask,
            We1 + (size_t)l * 258 * CC + 256 * CC,   // rows 256,257: w_rad, w_ea
            We2 + (size_t)l * CC * CC, be2 + l * CC,
            Wa + l * CC, ba + l,
            Wc1 + (size_t)l * CC * CC, bc1 + l * CC,
            Wc2 + l * CC,
            xn, agg);
        egnn_node<<<256, 128, 0, stream>>>(h, agg, nmask,
                                           Wn1 + (size_t)l * 2 * CC * CC, bn1 + l * CC,
                                           Wn2 + (size_t)l * CC * CC, bn2 + l * CC);
        float* tmp = xc; xc = xn; xn = tmp;
    }
    egnn_final<<<16, 128, 0, stream>>>(xc, xf, nmask, out);
}

// Round 10
// 702.377 us; speedup vs baseline: 1.4819x; 1.3397x over previous
//
#include <hip/hip_runtime.h>
#include <math.h>

#define CC 128   // channels
// B=16, N=128 per graph, BN=2048 nodes, L=3 layers
// Edge kernel: MFMA split-bf16 (3-term) for both 128^3 GEMMs.

typedef float  f32x4  __attribute__((ext_vector_type(4)));
typedef short  s16x8  __attribute__((ext_vector_type(8)));
typedef __bf16 bf16x8 __attribute__((ext_vector_type(8)));

__device__ __forceinline__ float fsilu(float x) { return x / (1.0f + __expf(-x)); }
__device__ __forceinline__ float fsigm(float x) { return 1.0f / (1.0f + __expf(-x)); }
__device__ __forceinline__ float ftanh_(float x) { return 1.0f - 2.0f / (__expf(2.0f * x) + 1.0f); }

// Split fp32 -> bf16 hi + bf16 lo (RNE both). x ~= hi + lo with ~2^-16 rel err.
__device__ __forceinline__ void bsplit(float x, short& hi, short& lo) {
    unsigned xu = __float_as_uint(x);
    unsigned hr = (xu + 0x7FFFu + ((xu >> 16) & 1u)) & 0xFFFF0000u;
    float hf = __uint_as_float(hr);
    float r = x - hf;
    unsigned ru = __float_as_uint(r);
    unsigned lr = ru + 0x7FFFu + ((ru >> 16) & 1u);
    hi = (short)(hr >> 16);
    lo = (short)(lr >> 16);
}

__device__ __forceinline__ f32x4 mfma16(s16x8 a, s16x8 b, f32x4 c) {
    return __builtin_amdgcn_mfma_f32_16x16x32_bf16(
        __builtin_bit_cast(bf16x8, a), __builtin_bit_cast(bf16x8, b), c, 0, 0, 0);
}

// ---------------------------------------------------------------- init ------
__global__ __launch_bounds__(128) void egnn_init(
    const float* __restrict__ t, const float* __restrict__ x,
    const int* __restrict__ atomt, const int* __restrict__ aapos,
    const int* __restrict__ aatype, const int* __restrict__ slen,
    const float* __restrict__ nmask, const float* __restrict__ embW,
    const float* __restrict__ embB, float* __restrict__ h,
    float* __restrict__ xf, float* __restrict__ xA)
{
    const int n = blockIdx.x;
    const int c = threadIdx.x;
    const int b = n >> 7;
    const int i = n & 127;
    const float mi = nmask[n];
    int ia = atomt[n] - 1; if (ia < 0) ia = 0;
    int ip = aapos[n] - 1; if (ip < 0) ip = 0;
    int iq = aatype[n] - 1; if (iq < 0) iq = 0;
    int is = slen[b] - 5;  if (is < 0) is = 0;
    const float tt = t[b] * mi;
    float v = mi * (embW[ia * CC + c] + embW[(54 + ip) * CC + c] +
                    embW[(84 + iq) * CC + c] + embW[(104 + is) * CC + c]) +
              tt * embW[130 * CC + c] + embB[c];
    h[(size_t)n * CC + c] = v;
    if (c < 3) {
        float xv = x[b * 384 + i * 3 + c] * mi;
        xf[3 * n + c] = xv;
        xA[3 * n + c] = xv;
    }
}

// ------------------------------------------------------- weight prep --------
// For layer l and mat in {We2, Wc1}: write W^T as bf16 hi/lo planes [n][k].
// wt layout (shorts): (l*2+mat)*32768 : [0,16384) = hi, [16384,32768) = lo.
__global__ __launch_bounds__(128) void egnn_wtprep(
    const float* __restrict__ We2, const float* __restrict__ Wc1,
    short* __restrict__ wt)
{
    const int blk = blockIdx.x;          // 96 = 3 layers x 2 mats x 16 chunks
    const int l = blk >> 5;
    const int mat = (blk >> 4) & 1;
    const int chunk = blk & 15;
    const int k = threadIdx.x;
    const float* W = (mat == 0 ? We2 : Wc1) + (size_t)l * CC * CC;
    short* hi = wt + (size_t)(l * 2 + mat) * 32768;
    short* lo = hi + 16384;
#pragma unroll
    for (int nn = 0; nn < 8; ++nn) {
        const int n = chunk * 8 + nn;
        short h_, l_;
        bsplit(W[k * CC + n], h_, l_);
        hi[n * CC + k] = h_;
        lo[n * CC + k] = l_;
    }
}

// ---------------------------------------------------------------- P,Q -------
// 2 nodes per block (1024 blocks) for occupancy.
__global__ __launch_bounds__(128) void egnn_pq(
    const float* __restrict__ h, const float* __restrict__ We1,
    const float* __restrict__ be1, float* __restrict__ P, float* __restrict__ Q)
{
    __shared__ float hs[2][CC];
    const int c = threadIdx.x;
    const int n0 = blockIdx.x * 2;
    hs[0][c] = h[(size_t)n0 * CC + c];
    hs[1][c] = h[(size_t)(n0 + 1) * CC + c];
    __syncthreads();
    const float bv = be1[c];
    float p0 = bv, p1 = bv, q0 = 0.f, q1 = 0.f;
#pragma unroll 4
    for (int k = 0; k < CC; ++k) {
        const float wr = We1[k * CC + c];
        const float wc = We1[(CC + k) * CC + c];
        p0 = fmaf(hs[0][k], wr, p0); p1 = fmaf(hs[1][k], wr, p1);
        q0 = fmaf(hs[0][k], wc, q0); q1 = fmaf(hs[1][k], wc, q1);
    }
    P[(size_t)n0 * CC + c] = p0; P[(size_t)(n0 + 1) * CC + c] = p1;
    Q[(size_t)n0 * CC + c] = q0; Q[(size_t)(n0 + 1) * CC + c] = q1;
}

// ---------------------------------------------------------------- edge ------
// One block per (graph b, row i): 128 edges (i,j). 256 thr = 4 waves.
// Wave w owns j-strip [32w, 32w+32): 2 M-tiles x 8 N-tiles of 16x16 MFMA.
// gemm1: M2 = M1 @ We2   (A = M1 in regs from phase A; B = We2^T hi/lo, global)
// gemm2: C2 = m @ Wc1    (A = m from LDS hi/lo planes; B = Wc1^T hi/lo, global)
__global__ __launch_bounds__(256, 2) void egnn_edge(
    const float* __restrict__ P, const float* __restrict__ Q,
    const float* __restrict__ xcur, const float* __restrict__ xf,
    const float* __restrict__ nmask, const float* __restrict__ We1t,
    const short* __restrict__ w1hiP, const short* __restrict__ w2hiP,
    const float* __restrict__ be2, const float* __restrict__ Wa,
    const float* __restrict__ ba, const float* __restrict__ bc1,
    const float* __restrict__ Wc2,
    float* __restrict__ xnext, float* __restrict__ agg)
{
    extern __shared__ char smraw[];
    short* mhi = (short*)smraw;           // 128x128 shorts (swizzled)
    short* mlo = mhi + 16384;
    float* fb    = (float*)(mlo + 16384);
    float* diffs = fb;                    // 384
    float* rjs   = fb + 384;              // 128
    float* eas   = fb + 512;              // 128
    float* emks  = fb + 640;              // 128
    float* pis   = fb + 768;              // 128
    float* wrads = fb + 896;              // 128
    float* weas  = fb + 1024;             // 128
    float* wass  = fb + 1152;             // 128
    float* wc2s  = fb + 1280;             // 128
    float* be2s  = fb + 1408;             // 128
    float* bc1s  = fb + 1536;             // 128
    float* aggp  = fb + 1664;             // 4*128
    float* trp   = fb + 2176;             // 16*4
    // total 65536 B + 2240*4 B = 74496 B

    const int tid = threadIdx.x;
    const int w  = tid >> 6;
    const int lane = tid & 63;
    const int g  = lane >> 4;            // 0..3
    const int lj = lane & 15;            // 0..15
    const int n = blockIdx.x;
    const int b = n >> 7;
    const int i = n & 127;
    const int nb = b << 7;
    const float mi = nmask[n];

    const short* w1lo = w1hiP + 16384;
    const short* w2lo = w2hiP + 16384;

    if (tid < 128) {
        const int j = tid;
        const float xi0 = xcur[3 * n], xi1 = xcur[3 * n + 1], xi2 = xcur[3 * n + 2];
        const float xj0 = xcur[3 * (nb + j)], xj1 = xcur[3 * (nb + j) + 1], xj2 = xcur[3 * (nb + j) + 2];
        const float d0 = xi0 - xj0, d1 = xi1 - xj1, d2 = xi2 - xj2;
        diffs[3 * j] = d0; diffs[3 * j + 1] = d1; diffs[3 * j + 2] = d2;
        rjs[j] = d0 * d0 + d1 * d1 + d2 * d2;
        const float f0 = xf[3 * n] - xf[3 * (nb + j)];
        const float f1 = xf[3 * n + 1] - xf[3 * (nb + j) + 1];
        const float f2 = xf[3 * n + 2] - xf[3 * (nb + j) + 2];
        eas[j] = f0 * f0 + f1 * f1 + f2 * f2;
        emks[j] = mi * nmask[nb + j] * ((j == i) ? 0.0f : 1.0f);
    } else {
        const int c = tid - 128;
        pis[c]   = P[(size_t)n * CC + c];
        wrads[c] = We1t[c];
        weas[c]  = We1t[CC + c];
        wass[c]  = Wa[c];
        wc2s[c]  = Wc2[c];
        be2s[c]  = be2[c];
        bc1s[c]  = bc1[c];
    }
    __syncthreads();

    // ---- Phase A: M1 computed directly into A-fragment registers ----------
    // lane holds M1[j = 32w+16mt+lj][k = 32kt+8g .. +8) split into hi/lo.
    s16x8 ahi[2][4], alo[2][4];
#pragma unroll
    for (int mt = 0; mt < 2; ++mt) {
        const int j = (w << 5) + (mt << 4) + lj;
        const float r  = rjs[j];
        const float ea = eas[j];
        const float* Qj = Q + (size_t)(nb + j) * CC;
#pragma unroll
        for (int kt = 0; kt < 4; ++kt) {
            const int c0 = (kt << 5) + (g << 3);
            const float4 q0 = *reinterpret_cast<const float4*>(Qj + c0);
            const float4 q1 = *reinterpret_cast<const float4*>(Qj + c0 + 4);
            const float4 p0 = *reinterpret_cast<const float4*>(pis + c0);
            const float4 p1 = *reinterpret_cast<const float4*>(pis + c0 + 4);
            const float4 r0 = *reinterpret_cast<const float4*>(wrads + c0);
            const float4 r1 = *reinterpret_cast<const float4*>(wrads + c0 + 4);
            const float4 e0 = *reinterpret_cast<const float4*>(weas + c0);
            const float4 e1 = *reinterpret_cast<const float4*>(weas + c0 + 4);
            float vv[8];
            vv[0] = fsilu(p0.x + q0.x + r * r0.x + ea * e0.x);
            vv[1] = fsilu(p0.y + q0.y + r * r0.y + ea * e0.y);
            vv[2] = fsilu(p0.z + q0.z + r * r0.z + ea * e0.z);
            vv[3] = fsilu(p0.w + q0.w + r * r0.w + ea * e0.w);
            vv[4] = fsilu(p1.x + q1.x + r * r1.x + ea * e1.x);
            vv[5] = fsilu(p1.y + q1.y + r * r1.y + ea * e1.y);
            vv[6] = fsilu(p1.z + q1.z + r * r1.z + ea * e1.z);
            vv[7] = fsilu(p1.w + q1.w + r * r1.w + ea * e1.w);
#pragma unroll
            for (int e = 0; e < 8; ++e) {
                short h_, l_;
                bsplit(vv[e], h_, l_);
                ahi[mt][kt][e] = h_;
                alo[mt][kt][e] = l_;
            }
        }
    }

    // ---- gemm1: acc[mt][nt] = M1 @ We2 (3-term split) ---------------------
    f32x4 acc[2][8];
#pragma unroll
    for (int mt = 0; mt < 2; ++mt)
#pragma unroll
        for (int nt = 0; nt < 8; ++nt) acc[mt][nt] = (f32x4){0.f, 0.f, 0.f, 0.f};
#pragma unroll
    for (int kt = 0; kt < 4; ++kt) {
#pragma unroll
        for (int nt = 0; nt < 8; ++nt) {
            const int wo = ((nt << 4) + lj) * CC + (kt << 5) + (g << 3);
            const s16x8 bh = *reinterpret_cast<const s16x8*>(w1hiP + wo);
            const s16x8 bl = *reinterpret_cast<const s16x8*>(w1lo + wo);
#pragma unroll
            for (int mt = 0; mt < 2; ++mt) {
                acc[mt][nt] = mfma16(ahi[mt][kt], bh, acc[mt][nt]);
                acc[mt][nt] = mfma16(ahi[mt][kt], bl, acc[mt][nt]);
                acc[mt][nt] = mfma16(alo[mt][kt], bh, acc[mt][nt]);
            }
        }
    }

    // ---- epilogue 1: silu + attention gate + agg + m -> LDS ---------------
    // D-frag: row j = 32w+16mt+4g+r, col c = 16nt+lj.
    float pa[2][4];
#pragma unroll
    for (int mt = 0; mt < 2; ++mt)
#pragma unroll
        for (int r = 0; r < 4; ++r) pa[mt][r] = 0.f;
#pragma unroll
    for (int mt = 0; mt < 2; ++mt)
#pragma unroll
        for (int nt = 0; nt < 8; ++nt) {
            const int c = (nt << 4) + lj;
            const float be = be2s[c], wa = wass[c];
#pragma unroll
            for (int r = 0; r < 4; ++r) {
                const float v = fsilu(acc[mt][nt][r] + be);
                acc[mt][nt][r] = v;
                pa[mt][r] = fmaf(v, wa, pa[mt][r]);
            }
        }
#pragma unroll
    for (int o = 1; o < 16; o <<= 1)
#pragma unroll
        for (int mt = 0; mt < 2; ++mt)
#pragma unroll
            for (int r = 0; r < 4; ++r) pa[mt][r] += __shfl_xor(pa[mt][r], o, 64);
    const float bav = ba[0];
    float gate[2][4];
#pragma unroll
    for (int mt = 0; mt < 2; ++mt)
#pragma unroll
        for (int r = 0; r < 4; ++r) {
            const int j = (w << 5) + (mt << 4) + (g << 2) + r;
            gate[mt][r] = fsigm(pa[mt][r] + bav) * emks[j];
        }
    float ap[8];
#pragma unroll
    for (int nt = 0; nt < 8; ++nt) ap[nt] = 0.f;
#pragma unroll
    for (int mt = 0; mt < 2; ++mt)
#pragma unroll
        for (int nt = 0; nt < 8; ++nt) {
            const int c = (nt << 4) + lj;
#pragma unroll
            for (int r = 0; r < 4; ++r) {
                const float mval = acc[mt][nt][r] * gate[mt][r];
                ap[nt] += mval;
                short h_, l_;
                bsplit(mval, h_, l_);
                const int j = (w << 5) + (mt << 4) + (g << 2) + r;
                const int idx = j * CC + (c ^ ((j & 7) << 3));
                mhi[idx] = h_;
                mlo[idx] = l_;
            }
        }
#pragma unroll
    for (int o = 16; o < 64; o <<= 1)
#pragma unroll
        for (int nt = 0; nt < 8; ++nt) ap[nt] += __shfl_xor(ap[nt], o, 64);
    if (g == 0) {
#pragma unroll
        for (int nt = 0; nt < 8; ++nt) aggp[(w << 7) + (nt << 4) + lj] = ap[nt];
    }
    __syncthreads();

    if (tid < 128) {
        agg[(size_t)n * CC + tid] =
            aggp[tid] + aggp[128 + tid] + aggp[256 + tid] + aggp[384 + tid];
    }

    // ---- gemm2: acc2 = m @ Wc1 (A from LDS m-planes, wave-local rows) -----
    s16x8 a2h[2][4], a2l[2][4];
#pragma unroll
    for (int mt = 0; mt < 2; ++mt) {
        const int j = (w << 5) + (mt << 4) + lj;
#pragma unroll
        for (int kt = 0; kt < 4; ++kt) {
            const int ofs = j * CC + ((((kt << 5) + (g << 3))) ^ ((j & 7) << 3));
            a2h[mt][kt] = *reinterpret_cast<const s16x8*>(mhi + ofs);
            a2l[mt][kt] = *reinterpret_cast<const s16x8*>(mlo + ofs);
        }
    }
    f32x4 acc2[2][8];
#pragma unroll
    for (int mt = 0; mt < 2; ++mt)
#pragma unroll
        for (int nt = 0; nt < 8; ++nt) acc2[mt][nt] = (f32x4){0.f, 0.f, 0.f, 0.f};
#pragma unroll
    for (int kt = 0; kt < 4; ++kt) {
#pragma unroll
        for (int nt = 0; nt < 8; ++nt) {
            const int wo = ((nt << 4) + lj) * CC + (kt << 5) + (g << 3);
            const s16x8 bh = *reinterpret_cast<const s16x8*>(w2hiP + wo);
            const s16x8 bl = *reinterpret_cast<const s16x8*>(w2lo + wo);
#pragma unroll
            for (int mt = 0; mt < 2; ++mt) {
                acc2[mt][nt] = mfma16(a2h[mt][kt], bh, acc2[mt][nt]);
                acc2[mt][nt] = mfma16(a2h[mt][kt], bl, acc2[mt][nt]);
                acc2[mt][nt] = mfma16(a2l[mt][kt], bh, acc2[mt][nt]);
            }
        }
    }

    // ---- epilogue 2: silu(+bc1)*Wc2 -> tanh -> trans ----------------------
    float dt[2][4];
#pragma unroll
    for (int mt = 0; mt < 2; ++mt)
#pragma unroll
        for (int r = 0; r < 4; ++r) dt[mt][r] = 0.f;
#pragma unroll
    for (int mt = 0; mt < 2; ++mt)
#pragma unroll
        for (int nt = 0; nt < 8; ++nt) {
            const int c = (nt << 4) + lj;
            const float bc = bc1s[c], wc = wc2s[c];
#pragma unroll
            for (int r = 0; r < 4; ++r)
                dt[mt][r] = fmaf(fsilu(acc2[mt][nt][r] + bc), wc, dt[mt][r]);
        }
#pragma unroll
    for (int o = 1; o < 16; o <<= 1)
#pragma unroll
        for (int mt = 0; mt < 2; ++mt)
#pragma unroll
            for (int r = 0; r < 4; ++r) dt[mt][r] += __shfl_xor(dt[mt][r], o, 64);
    if (lj == 0) {
        float t0 = 0.f, t1 = 0.f, t2 = 0.f;
#pragma unroll
        for (int mt = 0; mt < 2; ++mt)
#pragma unroll
            for (int r = 0; r < 4; ++r) {
                const int j = (w << 5) + (mt << 4) + (g << 2) + r;
                const float ts = ftanh_(dt[mt][r]);
                t0 = fmaf(diffs[3 * j    ], ts, t0);
                t1 = fmaf(diffs[3 * j + 1], ts, t1);
                t2 = fmaf(diffs[3 * j + 2], ts, t2);
            }
        const int slot = (w << 2) + g;
        trp[slot * 4 + 0] = t0; trp[slot * 4 + 1] = t1; trp[slot * 4 + 2] = t2;
    }
    __syncthreads();
    if (tid < 3) {
        float s = 0.f;
#pragma unroll
        for (int q = 0; q < 16; ++q) s += trp[q * 4 + tid];
        xnext[3 * n + tid] = (xcur[3 * n + tid] + s) * mi;
    }
}

// ---------------------------------------------------------------- node ------
// 2 nodes per block (1024 blocks).
__global__ __launch_bounds__(128) void egnn_node(
    float* __restrict__ h, const float* __restrict__ agg,
    const float* __restrict__ nmask,
    const float* __restrict__ Wn1, const float* __restrict__ bn1,
    const float* __restrict__ Wn2, const float* __restrict__ bn2)
{
    __shared__ float hs[2][CC], as_[2][CC], hn[2][CC];
    const int c = threadIdx.x;
    const int n0 = blockIdx.x * 2;
    hs[0][c] = h[(size_t)n0 * CC + c];
    hs[1][c] = h[(size_t)(n0 + 1) * CC + c];
    as_[0][c] = agg[(size_t)n0 * CC + c];
    as_[1][c] = agg[(size_t)(n0 + 1) * CC + c];
    __syncthreads();
    float a0 = bn1[c], a1 = a0;
#pragma unroll 4
    for (int k = 0; k < CC; ++k) {
        const float wv = Wn1[k * CC + c];
        a0 = fmaf(hs[0][k], wv, a0); a1 = fmaf(hs[1][k], wv, a1);
    }
#pragma unroll 4
    for (int k = 0; k < CC; ++k) {
        const float wv = Wn1[(CC + k) * CC + c];
        a0 = fmaf(as_[0][k], wv, a0); a1 = fmaf(as_[1][k], wv, a1);
    }
    hn[0][c] = fsilu(a0); hn[1][c] = fsilu(a1);
    __syncthreads();
    a0 = bn2[c]; a1 = a0;
#pragma unroll 4
    for (int k = 0; k < CC; ++k) {
        const float wv = Wn2[k * CC + c];
        a0 = fmaf(hn[0][k], wv, a0); a1 = fmaf(hn[1][k], wv, a1);
    }
    h[(size_t)n0 * CC + c]       = (hs[0][c] + a0) * nmask[n0];
    h[(size_t)(n0 + 1) * CC + c] = (hs[1][c] + a1) * nmask[n0 + 1];
}

// ---------------------------------------------------------------- final -----
__global__ __launch_bounds__(128) void egnn_final(
    const float* __restrict__ xcur, const float* __restrict__ xf,
    const float* __restrict__ nmask, float* __restrict__ out)
{
    __shared__ float red[128][4];
    const int i = threadIdx.x, b = blockIdx.x;
    const int n = b * 128 + i;
    const float mi = nmask[n];
    const float v0 = (xcur[3 * n    ] - xf[3 * n    ]) * mi;
    const float v1 = (xcur[3 * n + 1] - xf[3 * n + 1]) * mi;
    const float v2 = (xcur[3 * n + 2] - xf[3 * n + 2]) * mi;
    red[i][0] = v0; red[i][1] = v1; red[i][2] = v2; red[i][3] = mi;
    __syncthreads();
    for (int s = 64; s > 0; s >>= 1) {
        if (i < s) {
            red[i][0] += red[i + s][0]; red[i][1] += red[i + s][1];
            red[i][2] += red[i + s][2]; red[i][3] += red[i + s][3];
        }
        __syncthreads();
    }
    const float inv = 1.0f / red[0][3];
    out[b * 384 + i * 3 + 0] = v0 - red[0][0] * inv * mi;
    out[b * 384 + i * 3 + 1] = v1 - red[0][1] * inv * mi;
    out[b * 384 + i * 3 + 2] = v2 - red[0][2] * inv * mi;
}

// ---------------------------------------------------------------- host ------
extern "C" void kernel_launch(void* const* d_in, const int* in_sizes, int n_in,
                              void* d_out, int out_size, void* d_ws, size_t ws_size,
                              hipStream_t stream) {
    const float* t     = (const float*)d_in[0];
    const float* x     = (const float*)d_in[1];
    const int*   atomt = (const int*)d_in[2];
    const int*   aapos = (const int*)d_in[3];
    const int*   aatyp = (const int*)d_in[4];
    const int*   slen  = (const int*)d_in[5];
    const float* nmask = (const float*)d_in[6];
    const float* embW  = (const float*)d_in[7];
    const float* embB  = (const float*)d_in[8];
    const float* We1   = (const float*)d_in[9];
    const float* be1   = (const float*)d_in[10];
    const float* We2   = (const float*)d_in[11];
    const float* be2   = (const float*)d_in[12];
    const float* Wa    = (const float*)d_in[13];
    const float* ba    = (const float*)d_in[14];
    const float* Wn1   = (const float*)d_in[15];
    const float* bn1   = (const float*)d_in[16];
    const float* Wn2   = (const float*)d_in[17];
    const float* bn2   = (const float*)d_in[18];
    const float* Wc1   = (const float*)d_in[19];
    const float* bc1   = (const float*)d_in[20];
    const float* Wc2   = (const float*)d_in[21];

    float* ws  = (float*)d_ws;
    float* h   = ws;                 // 2048*128
    float* P   = ws + 262144;        // 2048*128
    float* Q   = ws + 524288;        // 2048*128
    float* agg = ws + 786432;        // 2048*128
    float* xA  = ws + 1048576;       // 2048*3
    float* xB  = ws + 1054720;       // 2048*3
    float* xf  = ws + 1060864;       // 2048*3
    short* wt  = (short*)(ws + 1067008); // 6 mats * 32768 shorts = 384 KB
    float* out = (float*)d_out;

    egnn_init<<<2048, 128, 0, stream>>>(t, x, atomt, aapos, aatyp, slen, nmask,
                                        embW, embB, h, xf, xA);
    egnn_wtprep<<<96, 128, 0, stream>>>(We2, Wc1, wt);

    const size_t edge_lds = 65536 + 2240 * sizeof(float);  // 74,496 B
    float* xc = xA;
    float* xn = xB;
    for (int l = 0; l < 3; ++l) {
        egnn_pq<<<1024, 128, 0, stream>>>(h, We1 + (size_t)l * 258 * CC,
                                          be1 + l * CC, P, Q);
        egnn_edge<<<2048, 256, edge_lds, stream>>>(
            P, Q, xc, xf, nmask,
            We1 + (size_t)l * 258 * CC + 256 * CC,   // rows 256,257: w_rad, w_ea
            wt + (size_t)(l * 2 + 0) * 32768,        // We2^T hi (lo at +16384)
            wt + (size_t)(l * 2 + 1) * 32768,        // Wc1^T hi (lo at +16384)
            be2 + l * CC, Wa + l * CC, ba + l, bc1 + l * CC, Wc2 + l * CC,
            xn, agg);
        egnn_node<<<1024, 128, 0, stream>>>(h, agg, nmask,
                                            Wn1 + (size_t)l * 2 * CC * CC, bn1 + l * CC,
                                            Wn2 + (size_t)l * CC * CC, bn2 + l * CC);
        float* tmp = xc; xc = xn; xn = tmp;
    }
    egnn_final<<<16, 128, 0, stream>>>(xc, xf, nmask, out);
}